// Round 1
// baseline (245.220 us; speedup 1.0000x reference)
//
#include <hip/hip_runtime.h>

// DetectionLoss: B=32768, G=7, A=2, C=3, M=20.
// R4 structure (from R3, harness-verified 178.1us):
//  - Obj-logit loads (7/thread) hoisted ABOVE Phase 1 so HBM latency hides
//    under assignment + dedup work instead of serializing after two barriers.
//  - Reduce kernel fused away: block partials atomicAdd'ed into ws (device
//    scope, cross-XCD safe), ticket counter, last block finalizes out[0]
//    reading totals via atomicAdd(p, 0.f) to stay in the coherent atomic path.
//  - Everything else byte-identical to the verified R3 logic:
//    Phase 1 per-target assignment -> LDS; Phase 1b last-write-wins dedup +
//    compaction; Phase 2 branchless noobj stream; Phase 2b compacted
//    positives with noobj correction (sp(-x) = sp(x) - x).

namespace {
constexpr int kG = 7;
constexpr int kA = 2;
constexpr int kM = 20;
constexpr int kCells = kG * kG * kA;     // 98
constexpr int kCh = 8;                   // 5 + C
constexpr int kNB = 32;                  // batches per block
constexpr int kBlock = 448;              // 7 waves; kNB*kCells/kBlock == 7 exactly
constexpr int kTgt = kNB * kM;           // 640
constexpr int kIters = (kNB * kCells) / kBlock;  // 7
}

__device__ __forceinline__ float softplus_fast(float x) {
    // logaddexp(x,0); fast exp/log — absmax threshold leaves huge slack
    return fmaxf(x, 0.0f) + __logf(1.0f + __expf(-fabsf(x)));
}

__global__ __launch_bounds__(kBlock) void det_loss_fused(
    const float* __restrict__ preds,
    const float* __restrict__ tboxes,
    const int* __restrict__ tlabels,
    const int* __restrict__ nobjs,
    const float* __restrict__ anchors,
    const float* __restrict__ cweights,
    float* __restrict__ ws,     // [0..4] totals (obj,noobj,bbox,cls,npos), [5] ticket; memset 0
    float* __restrict__ out,
    int B)
{
    __shared__ float4 s_tv[kTgt];        // per-target (tx,ty,tw,th)
    __shared__ short  s_cell[kTgt];      // block-local cell = bl*98+c, -1 invalid
    __shared__ int    s_pos[kTgt];       // compacted winners: (j<<16)|cell
    __shared__ int    s_nobj[kNB];
    __shared__ int    s_npos;
    __shared__ float  s_red[kBlock / 64][4];

    const int tid = threadIdx.x;
    const int b0 = blockIdx.x * kNB;

    if (tid < kNB) {
        const int b = b0 + tid;
        s_nobj[tid] = (b < B) ? nobjs[b] : 0;
    }
    if (tid == 0) s_npos = 0;

    // ---- Hoisted Phase 2 loads: issue all obj-logit loads NOW so the
    // ~500-cycle HBM latency overlaps Phase 1 + dedup (no barrier between
    // issue and first use of s_nobj below; loads touch only preds).
    const float* __restrict__ pblk = preds + (size_t)b0 * kCells * kCh;
    const bool full = (b0 + kNB <= B);
    float po[kIters];
    if (full) {
        #pragma unroll
        for (int k = 0; k < kIters; ++k)
            po[k] = pblk[(size_t)(tid + k * kBlock) * kCh];
    }

    __syncthreads();

    const float a00 = anchors[0], a01 = anchors[1];
    const float a10 = anchors[2], a11 = anchors[3];

    // ---- Phase 1: per-target assignment ----
    for (int j = tid; j < kTgt; j += kBlock) {
        const int bl = j / kM;
        const int m  = j - bl * kM;
        short cell = -1;
        float4 tv = make_float4(0.f, 0.f, 0.f, 0.f);
        if (b0 + bl < B) {
            const float4 box = ((const float4*)tboxes)[(size_t)b0 * kM + j];
            const float x1 = box.x, y1 = box.y, x2 = box.z, y2 = box.w;
            const float cx = (x1 + x2) * 0.5f, cy = (y1 + y2) * 0.5f;
            const float w = x2 - x1, h = y2 - y1;
            if (w > 0.f && h > 0.f && m < s_nobj[bl]) {
                const int gi = min(max((int)floorf(cy * (float)kG), 0), kG - 1);
                const int gj = min(max((int)floorf(cx * (float)kG), 0), kG - 1);
                const float wg = w * (float)kG, hg = h * (float)kG;
                const float i0 = fminf(wg, a00) * fminf(hg, a01);
                const float u0 = wg * hg + a00 * a01 - i0;
                const float r0 = i0 / (u0 + 1e-6f);
                const float i1 = fminf(wg, a10) * fminf(hg, a11);
                const float u1 = wg * hg + a10 * a11 - i1;
                const float r1 = i1 / (u1 + 1e-6f);
                const int a = (r1 > r0) ? 1 : 0;   // argmax, first-max wins
                const float aw = a ? a10 : a00;
                const float ah = a ? a11 : a01;
                tv.x = cx * (float)kG - (float)gj;
                tv.y = cy * (float)kG - (float)gi;
                tv.z = __logf(fmaxf(wg, 0.01f) / (aw + 1e-6f));
                tv.w = __logf(fmaxf(hg, 0.01f) / (ah + 1e-6f));
                cell = (short)(bl * kCells + (gi * kG + gj) * kA + a);
            }
        }
        s_cell[j] = cell;
        s_tv[j] = tv;
    }
    __syncthreads();

    // ---- Phase 1b: dedup (last-write-wins) + compaction ----
    for (int j = tid; j < kTgt; j += kBlock) {
        const short c = s_cell[j];
        if (c >= 0) {
            const int bl = j / kM;
            const int m  = j - bl * kM;
            bool win = true;
            for (int m2 = m + 1; m2 < kM; ++m2) {
                if (s_cell[bl * kM + m2] == c) { win = false; break; }
            }
            if (win) {
                const int idx = atomicAdd(&s_npos, 1);
                s_pos[idx] = (j << 16) | (int)c;
            }
        }
    }
    __syncthreads();

    // ---- Phase 2: branchless noobj sum (loads already in flight) ----
    float accO = 0.f, accN = 0.f, accB = 0.f, accC = 0.f;
    if (full) {
        #pragma unroll
        for (int k = 0; k < kIters; ++k)
            accN += softplus_fast(po[k]);
    } else {
        const int ncell = (B - b0) * kCells;
        for (int i = tid; i < ncell; i += kBlock)
            accN += softplus_fast(pblk[(size_t)i * kCh]);
    }

    // ---- Phase 2b: compacted positives ----
    const int np = s_npos;
    const float cw0 = cweights[0], cw1 = cweights[1], cw2 = cweights[2];
    for (int t = tid; t < np; t += kBlock) {
        const int pk = s_pos[t];
        const int j  = pk >> 16;
        const int ci = pk & 0xFFFF;
        const float4* pc = (const float4*)(pblk + (size_t)ci * kCh);
        const float4 p0 = pc[0];
        const float4 p1 = pc[1];
        const float spp = softplus_fast(p0.x);
        accN -= spp;            // remove wrongly-added noobj term
        accO += spp - p0.x;     // softplus(-x) == softplus(x) - x
        const float4 tv = s_tv[j];
        float d, ad;
        d = p0.y - tv.x; ad = fabsf(d); accB += (ad < 1.f) ? 0.5f * d * d : ad - 0.5f;
        d = p0.z - tv.y; ad = fabsf(d); accB += (ad < 1.f) ? 0.5f * d * d : ad - 0.5f;
        d = p0.w - tv.z; ad = fabsf(d); accB += (ad < 1.f) ? 0.5f * d * d : ad - 0.5f;
        d = p1.x - tv.w; ad = fabsf(d); accB += (ad < 1.f) ? 0.5f * d * d : ad - 0.5f;
        const int lab = tlabels[(size_t)b0 * kM + j];
        const float c0 = p1.y, c1 = p1.z, c2 = p1.w;
        const float mx = fmaxf(c0, fmaxf(c1, c2));
        const float lse = mx + __logf(__expf(c0 - mx) + __expf(c1 - mx) + __expf(c2 - mx));
        const float logit = (lab == 0) ? c0 : ((lab == 1) ? c1 : c2);
        const float cwv   = (lab == 0) ? cw0 : ((lab == 1) ? cw1 : cw2);
        accC += cwv * (lse - logit);
    }

    // ---- Block reduce (4 float sums) ----
    float vals[4] = {accO, accN, accB, accC};
    #pragma unroll
    for (int k = 0; k < 4; ++k) {
        float v = vals[k];
        #pragma unroll
        for (int off = 32; off > 0; off >>= 1) v += __shfl_down(v, off, 64);
        vals[k] = v;
    }
    const int wave = tid >> 6;
    const int lane = tid & 63;
    if (lane == 0) {
        #pragma unroll
        for (int k = 0; k < 4; ++k) s_red[wave][k] = vals[k];
    }
    __syncthreads();

    // ---- Grid accumulation + last-block finalize ----
    if (tid == 0) {
        float t[4];
        #pragma unroll
        for (int k = 0; k < 4; ++k) {
            float s = 0.f;
            #pragma unroll
            for (int w = 0; w < kBlock / 64; ++w) s += s_red[w][k];
            t[k] = s;
        }
        atomicAdd(&ws[0], t[0]);
        atomicAdd(&ws[1], t[1]);
        atomicAdd(&ws[2], t[2]);
        atomicAdd(&ws[3], t[3]);
        atomicAdd(&ws[4], (float)np);
        __threadfence();
        int* ticket = (int*)(ws + 5);
        const int done = atomicAdd(ticket, 1);
        if (done == (int)gridDim.x - 1) {
            // Read totals through the atomic path (device-scope coherent).
            const float tO = atomicAdd(&ws[0], 0.0f);
            const float tN = atomicAdd(&ws[1], 0.0f);
            const float tB = atomicAdd(&ws[2], 0.0f);
            const float tC = atomicAdd(&ws[3], 0.0f);
            const float tP = atomicAdd(&ws[4], 0.0f);
            const float npv = fmaxf(tP, 1.0f);
            out[0] = (5.0f * tB + 1.0f * tO + 0.5f * tN + 2.0f * tC) / npv;
        }
    }
}

extern "C" void kernel_launch(void* const* d_in, const int* in_sizes, int n_in,
                              void* d_out, int out_size, void* d_ws, size_t ws_size,
                              hipStream_t stream) {
    const float* preds    = (const float*)d_in[0];
    const float* tboxes   = (const float*)d_in[1];
    const int*   tlabels  = (const int*)d_in[2];
    const int*   nobjs    = (const int*)d_in[3];
    const float* anchors  = (const float*)d_in[4];
    const float* cweights = (const float*)d_in[5];
    float* out = (float*)d_out;
    float* ws  = (float*)d_ws;   // 5 float totals + 1 int ticket = 24 bytes

    const int B = in_sizes[0] / (kCells * kCh);   // /784
    const int blocks = (B + kNB - 1) / kNB;

    hipMemsetAsync(ws, 0, 6 * sizeof(float), stream);
    det_loss_fused<<<blocks, kBlock, 0, stream>>>(
        preds, tboxes, tlabels, nobjs, anchors, cweights, ws, out, B);
}

// Round 2
// 219.713 us; speedup vs baseline: 1.1161x; 1.1161x over previous
//
#include <hip/hip_runtime.h>

// DetectionLoss: B=32768, G=7, A=2, C=3, M=20.
// R5: R3's verified phase structure (main kernel ~60us) + fused finalize with
// ZERO same-address atomic contention.
// R4 post-mortem: 5 fp32 atomicAdds to the SAME ws addresses from 1024 blocks
// serialized at the device-coherent point (~20ns each * 6144 = ~120us; smoking
// gun: WRITE_SIZE 192.188KB == 6150 * 32B). This version:
//  - each block atomicExch's its 5 partials into DISTINCT slots [5][nblocks]
//    (distinct addresses -> pipelined, no serialization, coherent-point visible
//    without relying on fence codegen),
//  - one ticket atomicAdd per block (arrival rate ~20M/s << service rate),
//  - last block reduces the slot array with distinct-address atomicAdd(p,0.f)
//    reads (proven-coherent read path from R4) across all 448 threads.
// Load hoist reverted: __syncthreads drains vmcnt(0), so hoisting bought nothing.

namespace {
constexpr int kG = 7;
constexpr int kA = 2;
constexpr int kM = 20;
constexpr int kCells = kG * kG * kA;     // 98
constexpr int kCh = 8;                   // 5 + C
constexpr int kNB = 32;                  // batches per block
constexpr int kBlock = 448;              // 7 waves; kNB*kCells/kBlock == 7 exactly
constexpr int kTgt = kNB * kM;           // 640
constexpr int kIters = (kNB * kCells) / kBlock;  // 7
}

__device__ __forceinline__ float softplus_fast(float x) {
    // logaddexp(x,0); fast exp/log — absmax threshold leaves huge slack
    return fmaxf(x, 0.0f) + __logf(1.0f + __expf(-fabsf(x)));
}

__global__ __launch_bounds__(kBlock) void det_loss_fused(
    const float* __restrict__ preds,
    const float* __restrict__ tboxes,
    const int* __restrict__ tlabels,
    const int* __restrict__ nobjs,
    const float* __restrict__ anchors,
    const float* __restrict__ cweights,
    float* __restrict__ partial,   // [5][nblocks] distinct slots
    int* __restrict__ ticket,      // zeroed by host each call
    float* __restrict__ out,
    int B, int nblocks)
{
    __shared__ float4 s_tv[kTgt];        // per-target (tx,ty,tw,th)
    __shared__ short  s_cell[kTgt];      // block-local cell = bl*98+c, -1 invalid
    __shared__ int    s_pos[kTgt];       // compacted winners: (j<<16)|cell
    __shared__ int    s_nobj[kNB];
    __shared__ int    s_npos;
    __shared__ float  s_red[kBlock / 64][5];
    __shared__ int    s_last;

    const int tid = threadIdx.x;
    const int b0 = blockIdx.x * kNB;

    if (tid < kNB) {
        const int b = b0 + tid;
        s_nobj[tid] = (b < B) ? nobjs[b] : 0;
    }
    if (tid == 0) s_npos = 0;
    __syncthreads();

    const float a00 = anchors[0], a01 = anchors[1];
    const float a10 = anchors[2], a11 = anchors[3];

    // ---- Phase 1: per-target assignment ----
    for (int j = tid; j < kTgt; j += kBlock) {
        const int bl = j / kM;
        const int m  = j - bl * kM;
        short cell = -1;
        float4 tv = make_float4(0.f, 0.f, 0.f, 0.f);
        if (b0 + bl < B) {
            const float4 box = ((const float4*)tboxes)[(size_t)b0 * kM + j];
            const float x1 = box.x, y1 = box.y, x2 = box.z, y2 = box.w;
            const float cx = (x1 + x2) * 0.5f, cy = (y1 + y2) * 0.5f;
            const float w = x2 - x1, h = y2 - y1;
            if (w > 0.f && h > 0.f && m < s_nobj[bl]) {
                const int gi = min(max((int)floorf(cy * (float)kG), 0), kG - 1);
                const int gj = min(max((int)floorf(cx * (float)kG), 0), kG - 1);
                const float wg = w * (float)kG, hg = h * (float)kG;
                const float i0 = fminf(wg, a00) * fminf(hg, a01);
                const float u0 = wg * hg + a00 * a01 - i0;
                const float r0 = i0 / (u0 + 1e-6f);
                const float i1 = fminf(wg, a10) * fminf(hg, a11);
                const float u1 = wg * hg + a10 * a11 - i1;
                const float r1 = i1 / (u1 + 1e-6f);
                const int a = (r1 > r0) ? 1 : 0;   // argmax, first-max wins
                const float aw = a ? a10 : a00;
                const float ah = a ? a11 : a01;
                tv.x = cx * (float)kG - (float)gj;
                tv.y = cy * (float)kG - (float)gi;
                tv.z = __logf(fmaxf(wg, 0.01f) / (aw + 1e-6f));
                tv.w = __logf(fmaxf(hg, 0.01f) / (ah + 1e-6f));
                cell = (short)(bl * kCells + (gi * kG + gj) * kA + a);
            }
        }
        s_cell[j] = cell;
        s_tv[j] = tv;
    }
    __syncthreads();

    // ---- Phase 1b: dedup (last-write-wins) + compaction ----
    for (int j = tid; j < kTgt; j += kBlock) {
        const short c = s_cell[j];
        if (c >= 0) {
            const int bl = j / kM;
            const int m  = j - bl * kM;
            bool win = true;
            for (int m2 = m + 1; m2 < kM; ++m2) {
                if (s_cell[bl * kM + m2] == c) { win = false; break; }
            }
            if (win) {
                const int idx = atomicAdd(&s_npos, 1);
                s_pos[idx] = (j << 16) | (int)c;
            }
        }
    }
    __syncthreads();

    // ---- Phase 2: branchless stream of all obj logits ----
    float accO = 0.f, accN = 0.f, accB = 0.f, accC = 0.f;
    const float* __restrict__ pblk = preds + (size_t)b0 * kCells * kCh;
    if (b0 + kNB <= B) {
        #pragma unroll
        for (int k = 0; k < kIters; ++k) {
            const float po = pblk[(size_t)(tid + k * kBlock) * kCh];
            accN += softplus_fast(po);
        }
    } else {
        const int ncell = (B - b0) * kCells;
        for (int i = tid; i < ncell; i += kBlock)
            accN += softplus_fast(pblk[(size_t)i * kCh]);
    }

    // ---- Phase 2b: compacted positives ----
    const int np = s_npos;
    const float cw0 = cweights[0], cw1 = cweights[1], cw2 = cweights[2];
    for (int t = tid; t < np; t += kBlock) {
        const int pk = s_pos[t];
        const int j  = pk >> 16;
        const int ci = pk & 0xFFFF;
        const float4* pc = (const float4*)(pblk + (size_t)ci * kCh);
        const float4 p0 = pc[0];
        const float4 p1 = pc[1];
        const float spp = softplus_fast(p0.x);
        accN -= spp;            // remove wrongly-added noobj term
        accO += spp - p0.x;     // softplus(-x) == softplus(x) - x
        const float4 tv = s_tv[j];
        float d, ad;
        d = p0.y - tv.x; ad = fabsf(d); accB += (ad < 1.f) ? 0.5f * d * d : ad - 0.5f;
        d = p0.z - tv.y; ad = fabsf(d); accB += (ad < 1.f) ? 0.5f * d * d : ad - 0.5f;
        d = p0.w - tv.z; ad = fabsf(d); accB += (ad < 1.f) ? 0.5f * d * d : ad - 0.5f;
        d = p1.x - tv.w; ad = fabsf(d); accB += (ad < 1.f) ? 0.5f * d * d : ad - 0.5f;
        const int lab = tlabels[(size_t)b0 * kM + j];
        const float c0 = p1.y, c1 = p1.z, c2 = p1.w;
        const float mx = fmaxf(c0, fmaxf(c1, c2));
        const float lse = mx + __logf(__expf(c0 - mx) + __expf(c1 - mx) + __expf(c2 - mx));
        const float logit = (lab == 0) ? c0 : ((lab == 1) ? c1 : c2);
        const float cwv   = (lab == 0) ? cw0 : ((lab == 1) ? cw1 : cw2);
        accC += cwv * (lse - logit);
    }

    // ---- Block reduce (4 float sums) ----
    float vals[4] = {accO, accN, accB, accC};
    #pragma unroll
    for (int k = 0; k < 4; ++k) {
        float v = vals[k];
        #pragma unroll
        for (int off = 32; off > 0; off >>= 1) v += __shfl_down(v, off, 64);
        vals[k] = v;
    }
    const int wave = tid >> 6;
    const int lane = tid & 63;
    if (lane == 0) {
        #pragma unroll
        for (int k = 0; k < 4; ++k) s_red[wave][k] = vals[k];
    }
    __syncthreads();

    // ---- Per-block distinct-slot publish + ticket ----
    if (tid == 0) {
        float t[4];
        #pragma unroll
        for (int k = 0; k < 4; ++k) {
            float s = 0.f;
            #pragma unroll
            for (int w = 0; w < kBlock / 64; ++w) s += s_red[w][k];
            t[k] = s;
        }
        // Distinct addresses per block: atomic writes land at the coherent
        // point, pipeline freely, and are readable via the atomic path below.
        atomicExch(&partial[(size_t)0 * nblocks + blockIdx.x], t[0]);
        atomicExch(&partial[(size_t)1 * nblocks + blockIdx.x], t[1]);
        atomicExch(&partial[(size_t)2 * nblocks + blockIdx.x], t[2]);
        atomicExch(&partial[(size_t)3 * nblocks + blockIdx.x], t[3]);
        atomicExch(&partial[(size_t)4 * nblocks + blockIdx.x], (float)np);
        __threadfence();
        const int done = atomicAdd(ticket, 1);
        s_last = (done == nblocks - 1) ? 1 : 0;
    }
    __syncthreads();

    // ---- Last block: reduce all slots and finalize ----
    if (s_last) {
        float v[5] = {0.f, 0.f, 0.f, 0.f, 0.f};
        for (int i = tid; i < nblocks; i += kBlock) {
            #pragma unroll
            for (int k = 0; k < 5; ++k)
                v[k] += atomicAdd(&partial[(size_t)k * nblocks + i], 0.0f);
        }
        #pragma unroll
        for (int k = 0; k < 5; ++k) {
            float x = v[k];
            #pragma unroll
            for (int off = 32; off > 0; off >>= 1) x += __shfl_down(x, off, 64);
            v[k] = x;
        }
        if (lane == 0) {
            #pragma unroll
            for (int k = 0; k < 5; ++k) s_red[wave][k] = v[k];
        }
        __syncthreads();
        if (tid == 0) {
            float t[5];
            #pragma unroll
            for (int k = 0; k < 5; ++k) {
                float s = 0.f;
                #pragma unroll
                for (int w = 0; w < kBlock / 64; ++w) s += s_red[w][k];
                t[k] = s;
            }
            const float npv = fmaxf(t[4], 1.0f);
            out[0] = (5.0f * t[2] + 1.0f * t[0] + 0.5f * t[1] + 2.0f * t[3]) / npv;
        }
    }
}

extern "C" void kernel_launch(void* const* d_in, const int* in_sizes, int n_in,
                              void* d_out, int out_size, void* d_ws, size_t ws_size,
                              hipStream_t stream) {
    const float* preds    = (const float*)d_in[0];
    const float* tboxes   = (const float*)d_in[1];
    const int*   tlabels  = (const int*)d_in[2];
    const int*   nobjs    = (const int*)d_in[3];
    const float* anchors  = (const float*)d_in[4];
    const float* cweights = (const float*)d_in[5];
    float* out = (float*)d_out;

    const int B = in_sizes[0] / (kCells * kCh);   // /784
    const int blocks = (B + kNB - 1) / kNB;

    float* partial = (float*)d_ws;                // [5][blocks]
    int*   ticket  = (int*)(partial + (size_t)5 * blocks);

    hipMemsetAsync(ticket, 0, sizeof(int), stream);
    det_loss_fused<<<blocks, kBlock, 0, stream>>>(
        preds, tboxes, tlabels, nobjs, anchors, cweights, partial, ticket, out, B, blocks);
}

// Round 3
// 184.555 us; speedup vs baseline: 1.3287x; 1.1905x over previous
//
#include <hip/hip_runtime.h>

// DetectionLoss: B=32768, G=7, A=2, C=3, M=20.
// R6: revert to R3's two-kernel structure (fused tail cost ~40us > 2nd launch;
// falsified twice: R4 same-address atomics +58us, R5 ticket-burst +40us), and
// fix the REAL bottleneck shown by counters (VALUBusy 7%, HBM 7.6%, latency-
// bound): Phase 2's 4B-stride-32B obj loads touched 32 lines/wave-instr with
// 8/64B used. Now: fully-coalesced float4 stream of the whole preds block
// (lane i -> base + i*16B, m13's 6.29 TB/s pattern), 14 float4/thread, obj
// extracted from even chunks' .x (tid parity is fixed since kBlock is even).
//  - Phase 1: per-target cell assignment (tv, cell) into LDS.
//  - Phase 1b: parallel dedup (last-write-wins) + LDS compaction into s_pos.
//  - Phase 2: coalesced float4 stream -> noobj sum (even threads only).
//  - Phase 2b: ~300 compacted positives/block: gather 32B, obj/bbox/cls terms,
//    noobj correction (-sp(po)); sp(-x) = sp(x) - x.
//  - Block partials plain-stored SoA (no atomics), tiny reduce kernel.

namespace {
constexpr int kG = 7;
constexpr int kA = 2;
constexpr int kM = 20;
constexpr int kCells = kG * kG * kA;     // 98
constexpr int kCh = 8;                   // 5 + C
constexpr int kNB = 32;                  // batches per block
constexpr int kBlock = 448;              // 7 waves
constexpr int kTgt = kNB * kM;           // 640
constexpr int kChunks = kNB * kCells * 2;          // 6272 float4 chunks/block
constexpr int kIters = kChunks / kBlock;           // 14 exactly
}

__device__ __forceinline__ float softplus_fast(float x) {
    // logaddexp(x,0); fast exp/log — absmax threshold leaves huge slack
    return fmaxf(x, 0.0f) + __logf(1.0f + __expf(-fabsf(x)));
}

__global__ __launch_bounds__(kBlock) void det_loss_main(
    const float* __restrict__ preds,
    const float* __restrict__ tboxes,
    const int* __restrict__ tlabels,
    const int* __restrict__ nobjs,
    const float* __restrict__ anchors,
    const float* __restrict__ cweights,
    float* __restrict__ partial,   // SoA [5][gridDim.x]: obj, noobj, bbox, cls, npos
    int B)
{
    __shared__ float4 s_tv[kTgt];        // per-target (tx,ty,tw,th)
    __shared__ short  s_cell[kTgt];      // block-local cell = bl*98+c, -1 invalid
    __shared__ int    s_pos[kTgt];       // compacted winners: (j<<16)|cell
    __shared__ int    s_nobj[kNB];
    __shared__ int    s_npos;
    __shared__ float  s_red[kBlock / 64][4];

    const int tid = threadIdx.x;
    const int b0 = blockIdx.x * kNB;

    if (tid < kNB) {
        const int b = b0 + tid;
        s_nobj[tid] = (b < B) ? nobjs[b] : 0;
    }
    if (tid == 0) s_npos = 0;
    __syncthreads();

    const float a00 = anchors[0], a01 = anchors[1];
    const float a10 = anchors[2], a11 = anchors[3];

    // ---- Phase 1: per-target assignment ----
    for (int j = tid; j < kTgt; j += kBlock) {
        const int bl = j / kM;
        const int m  = j - bl * kM;
        short cell = -1;
        float4 tv = make_float4(0.f, 0.f, 0.f, 0.f);
        if (b0 + bl < B) {
            const float4 box = ((const float4*)tboxes)[(size_t)b0 * kM + j];
            const float x1 = box.x, y1 = box.y, x2 = box.z, y2 = box.w;
            const float cx = (x1 + x2) * 0.5f, cy = (y1 + y2) * 0.5f;
            const float w = x2 - x1, h = y2 - y1;
            if (w > 0.f && h > 0.f && m < s_nobj[bl]) {
                const int gi = min(max((int)floorf(cy * (float)kG), 0), kG - 1);
                const int gj = min(max((int)floorf(cx * (float)kG), 0), kG - 1);
                const float wg = w * (float)kG, hg = h * (float)kG;
                const float i0 = fminf(wg, a00) * fminf(hg, a01);
                const float u0 = wg * hg + a00 * a01 - i0;
                const float r0 = i0 / (u0 + 1e-6f);
                const float i1 = fminf(wg, a10) * fminf(hg, a11);
                const float u1 = wg * hg + a10 * a11 - i1;
                const float r1 = i1 / (u1 + 1e-6f);
                const int a = (r1 > r0) ? 1 : 0;   // argmax, first-max wins
                const float aw = a ? a10 : a00;
                const float ah = a ? a11 : a01;
                tv.x = cx * (float)kG - (float)gj;
                tv.y = cy * (float)kG - (float)gi;
                tv.z = __logf(fmaxf(wg, 0.01f) / (aw + 1e-6f));
                tv.w = __logf(fmaxf(hg, 0.01f) / (ah + 1e-6f));
                cell = (short)(bl * kCells + (gi * kG + gj) * kA + a);
            }
        }
        s_cell[j] = cell;
        s_tv[j] = tv;
    }
    __syncthreads();

    // ---- Phase 1b: dedup (last-write-wins) + compaction ----
    for (int j = tid; j < kTgt; j += kBlock) {
        const short c = s_cell[j];
        if (c >= 0) {
            const int bl = j / kM;
            const int m  = j - bl * kM;
            bool win = true;
            for (int m2 = m + 1; m2 < kM; ++m2) {
                if (s_cell[bl * kM + m2] == c) { win = false; break; }
            }
            if (win) {
                const int idx = atomicAdd(&s_npos, 1);
                s_pos[idx] = (j << 16) | (int)c;
            }
        }
    }
    __syncthreads();

    // ---- Phase 2: fully-coalesced float4 stream of the whole preds block ----
    // Chunk c (16B) covers cell c/2; even chunks hold (obj, bx, by, bw).
    // tid + k*kBlock preserves parity (kBlock even) -> even threads always see
    // obj-bearing chunks; odd threads contribute nothing (predicated VALU).
    float accO = 0.f, accN = 0.f, accB = 0.f, accC = 0.f;
    const float* __restrict__ pblk = preds + (size_t)b0 * kCells * kCh;
    const float4* __restrict__ pblk4 = (const float4*)pblk;
    if (b0 + kNB <= B) {
        const bool hasObj = (tid & 1) == 0;
        #pragma unroll
        for (int k = 0; k < kIters; ++k) {
            const float4 v = pblk4[(size_t)(tid + k * kBlock)];
            if (hasObj) accN += softplus_fast(v.x);
        }
    } else {
        const int nchunk = (B - b0) * kCells * 2;
        const bool hasObj = (tid & 1) == 0;
        for (int i = tid; i < nchunk; i += kBlock) {
            const float4 v = pblk4[(size_t)i];
            if (hasObj) accN += softplus_fast(v.x);
        }
    }

    // ---- Phase 2b: compacted positives ----
    const int np = s_npos;
    const float cw0 = cweights[0], cw1 = cweights[1], cw2 = cweights[2];
    for (int t = tid; t < np; t += kBlock) {
        const int pk = s_pos[t];
        const int j  = pk >> 16;
        const int ci = pk & 0xFFFF;
        const float4* pc = (const float4*)(pblk + (size_t)ci * kCh);
        const float4 p0 = pc[0];
        const float4 p1 = pc[1];
        const float spp = softplus_fast(p0.x);
        accN -= spp;            // remove wrongly-added noobj term
        accO += spp - p0.x;     // softplus(-x) == softplus(x) - x
        const float4 tv = s_tv[j];
        float d, ad;
        d = p0.y - tv.x; ad = fabsf(d); accB += (ad < 1.f) ? 0.5f * d * d : ad - 0.5f;
        d = p0.z - tv.y; ad = fabsf(d); accB += (ad < 1.f) ? 0.5f * d * d : ad - 0.5f;
        d = p0.w - tv.z; ad = fabsf(d); accB += (ad < 1.f) ? 0.5f * d * d : ad - 0.5f;
        d = p1.x - tv.w; ad = fabsf(d); accB += (ad < 1.f) ? 0.5f * d * d : ad - 0.5f;
        const int lab = tlabels[(size_t)b0 * kM + j];
        const float c0 = p1.y, c1 = p1.z, c2 = p1.w;
        const float mx = fmaxf(c0, fmaxf(c1, c2));
        const float lse = mx + __logf(__expf(c0 - mx) + __expf(c1 - mx) + __expf(c2 - mx));
        const float logit = (lab == 0) ? c0 : ((lab == 1) ? c1 : c2);
        const float cwv   = (lab == 0) ? cw0 : ((lab == 1) ? cw1 : cw2);
        accC += cwv * (lse - logit);
    }

    // ---- Block reduce (4 float sums) + plain SoA stores ----
    float vals[4] = {accO, accN, accB, accC};
    #pragma unroll
    for (int k = 0; k < 4; ++k) {
        float v = vals[k];
        #pragma unroll
        for (int off = 32; off > 0; off >>= 1) v += __shfl_down(v, off, 64);
        vals[k] = v;
    }
    const int wave = tid >> 6;
    const int lane = tid & 63;
    if (lane == 0) {
        #pragma unroll
        for (int k = 0; k < 4; ++k) s_red[wave][k] = vals[k];
    }
    __syncthreads();
    if (tid == 0) {
        const int nb = gridDim.x;
        #pragma unroll
        for (int k = 0; k < 4; ++k) {
            float t = 0.f;
            #pragma unroll
            for (int w = 0; w < kBlock / 64; ++w) t += s_red[w][k];
            partial[(size_t)k * nb + blockIdx.x] = t;
        }
        partial[(size_t)4 * nb + blockIdx.x] = (float)np;   // num_pos
    }
}

__global__ __launch_bounds__(256) void det_loss_reduce(
    const float* __restrict__ partial, int nblocks, float* __restrict__ out)
{
    __shared__ float s_red[4][5];
    const int tid = threadIdx.x;
    float v[5] = {0.f, 0.f, 0.f, 0.f, 0.f};
    for (int i = tid; i < nblocks; i += 256) {
        #pragma unroll
        for (int k = 0; k < 5; ++k) v[k] += partial[(size_t)k * nblocks + i];
    }
    #pragma unroll
    for (int k = 0; k < 5; ++k) {
        float x = v[k];
        #pragma unroll
        for (int off = 32; off > 0; off >>= 1) x += __shfl_down(x, off, 64);
        v[k] = x;
    }
    const int wave = tid >> 6;
    const int lane = tid & 63;
    if (lane == 0) {
        #pragma unroll
        for (int k = 0; k < 5; ++k) s_red[wave][k] = v[k];
    }
    __syncthreads();
    if (tid == 0) {
        float t[5];
        #pragma unroll
        for (int k = 0; k < 5; ++k) {
            float s = 0.f;
            #pragma unroll
            for (int w = 0; w < 4; ++w) s += s_red[w][k];
            t[k] = s;
        }
        const float npv = fmaxf(t[4], 1.0f);
        out[0] = (5.0f * t[2] + 1.0f * t[0] + 0.5f * t[1] + 2.0f * t[3]) / npv;
    }
}

extern "C" void kernel_launch(void* const* d_in, const int* in_sizes, int n_in,
                              void* d_out, int out_size, void* d_ws, size_t ws_size,
                              hipStream_t stream) {
    const float* preds    = (const float*)d_in[0];
    const float* tboxes   = (const float*)d_in[1];
    const int*   tlabels  = (const int*)d_in[2];
    const int*   nobjs    = (const int*)d_in[3];
    const float* anchors  = (const float*)d_in[4];
    const float* cweights = (const float*)d_in[5];
    float* out = (float*)d_out;
    float* partial = (float*)d_ws;   // [5][nblocks], fully overwritten every call

    const int B = in_sizes[0] / (kCells * kCh);   // /784
    const int blocks = (B + kNB - 1) / kNB;

    det_loss_main<<<blocks, kBlock, 0, stream>>>(
        preds, tboxes, tlabels, nobjs, anchors, cweights, partial, B);
    det_loss_reduce<<<1, 256, 0, stream>>>(partial, blocks, out);
}